// Round 1
// baseline (263.592 us; speedup 1.0000x reference)
//
#include <hip/hip_runtime.h>
#include <stdint.h>

// ---------------- problem constants ----------------
#define GD 32
#define GH 512
#define GW 512
#define GDHW (GD * GH * GW)    // 8388608
#define KOFF 27
#define CAP 4096               // per-offset pair capacity (mean ~2685, sigma ~51)
#define CNTS 32                // counter stride in ints (128 B: one line each)
#define NW2 (KOFF * 128 * 128)

typedef __attribute__((ext_vector_type(8))) short short8;
typedef __attribute__((ext_vector_type(4))) float f32x4;

typedef const __attribute__((address_space(1))) unsigned int* gu32p;
typedef __attribute__((address_space(3))) unsigned int* lu32p;

__device__ __forceinline__ void async_load16(const void* g, void* l) {
    __builtin_amdgcn_global_load_lds((gu32p)g, (lu32p)l, 16, 0, 0);
}

__device__ __forceinline__ unsigned short f32_to_bf16(float x) {
    unsigned int u = __float_as_uint(x);
    unsigned int r = (u + 0x7FFFu + ((u >> 16) & 1u)) >> 16;
    return (unsigned short)r;
}

// ---------------- setup: scatter + w2prep + tiny zero-fills (fused) --------
// Replaces scatter_kernel, w2prep_kernel, memset(cnts), memset(zerop).
__global__ __launch_bounds__(256) void setup_kernel(
    const int* __restrict__ coors, int* __restrict__ grid,
    const float* __restrict__ w2, unsigned short* __restrict__ w2s,
    int* __restrict__ cnts, unsigned short* __restrict__ zerop,
    int n, int nbsc) {
    const int bid = blockIdx.x, t = threadIdx.x;
    if (bid == 0) {
        for (int q = t; q < 26 * CNTS; q += 256) cnts[q] = 0;
        if (t < 64) ((int*)zerop)[t] = 0;
    }
    if (bid < nbsc) {
        int i = bid * 256 + t;
        if (i < n) {
            int z = coors[i * 4 + 1];
            int y = coors[i * 4 + 2];
            int x = coors[i * 4 + 3];
            grid[(z * GH + y) * GW + x] = i;
        }
    } else {
        int g = (bid - nbsc) * 256 + t;
        if (g < NW2) {
            // w2  (f32)  : [27][128(cin)][128(cout)]
            // w2s (bf16) : [27][cout][16 chunks][8], chunk cc of row c holds
            //   source cin-chunk ((cc&7)^(c&7))|(cc&8)  (XOR-swizzled banks)
            int k = g >> 14;
            int c = (g >> 7) & 127;
            int idx = g & 127;
            int cc = idx >> 3, e = idx & 7;
            int scc = ((cc & 7) ^ (c & 7)) | (cc & 8);
            int cin = scc * 8 + e;
            w2s[g] = f32_to_bf16(w2[(k * 128 + cin) * 128 + c]);
        }
    }
}

// ---------------- nbr: SINGLE PASS, 26 branch-free probes (center j=i) ------
// Outputs:
//   vcnt[i] (all i<n written -> no memset), nbrc[i*27+s] = (k<<20)|j  -> conv1
//   pairs[kb][pos] = j                       -> conv2b A-gather
//   npos[i*27+s]   = kb*CAP+pos (or -1)      -> conv2a correction gather
__global__ __launch_bounds__(256) void nbr_kernel(
    const int* __restrict__ coors, const int* __restrict__ grid,
    int* __restrict__ vcnt, int* __restrict__ nbrc,
    int* __restrict__ pairs, int* __restrict__ npos,
    int* __restrict__ cnts, int n) {
    __shared__ int wcnt[4][26];
    __shared__ int kbase[26];

    const int i = blockIdx.x * 256 + threadIdx.x;
    const int t = threadIdx.x, wave = t >> 6, lane = t & 63;
    const bool live = (i < n);
    const unsigned long long lmask = (1ull << lane) - 1;

    int z = 0, y = 0, x = 0;
    if (live) {
        z = coors[i * 4 + 1];
        y = coors[i * 4 + 2];
        x = coors[i * 4 + 3];
    }

    // ---- phase 1: 26 branch-free clamped lookups (MLP=26) ----
    int j[27];
#pragma unroll
    for (int k = 0; k < 27; ++k) {
        if (k == 13) { j[k] = live ? i : -1; continue; }
        int dz = k / 9 - 1, dy = (k / 3) % 3 - 1, dx = k % 3 - 1;
        int nz = z + dz, ny = y + dy, nx = x + dx;
        int cz = min(max(nz, 0), GD - 1);
        int cy = min(max(ny, 0), GH - 1);
        int cx = min(max(nx, 0), GW - 1);
        int jj = grid[(cz * GH + cy) * GW + cx];   // always legal address
        bool ok = live && nz >= 0 && nz < GD && ny >= 0 && ny < GH &&
                  nx >= 0 && nx < GW;
        j[k] = ok ? jj : -1;
    }

    // ---- phase 2: per-voxel compacted list (single owner -> plain stores) --
    if (live) {
        int c = 0;
#pragma unroll
        for (int k = 0; k < 27; ++k) {
            if (k == 13) continue;
            if (j[k] >= 0) { nbrc[i * 27 + c] = (k << 20) | j[k]; ++c; }
        }
        vcnt[i] = c;
    }

    // ---- phase 3: per-offset pair buckets (block-aggregated atomic) ----
#pragma unroll
    for (int kk = 0; kk < 26; ++kk) {
        const int k = kk + (kk >= 13);
        unsigned long long m = __ballot(live && (j[k] >= 0));
        if (lane == 0) wcnt[wave][kk] = __popcll(m);
    }
    __syncthreads();
    if (t < 26) {
        int tot = wcnt[0][t] + wcnt[1][t] + wcnt[2][t] + wcnt[3][t];
        kbase[t] = (tot > 0) ? atomicAdd(&cnts[t * CNTS], tot) : 0;
    }
    __syncthreads();
    int slot = 0;
#pragma unroll
    for (int kk = 0; kk < 26; ++kk) {
        const int k = kk + (kk >= 13);
        const bool valid = live && (j[k] >= 0);
        unsigned long long m = __ballot(valid);
        if (valid) {
            int off = 0;
#pragma unroll
            for (int w = 0; w < 4; ++w)
                if (w < wave) off += wcnt[w][kk];
            int pos = kbase[kk] + off + __popcll(m & lmask);
            if (pos < CAP) {
                pairs[kk * CAP + pos] = j[k];
                npos[i * 27 + slot] = kk * CAP + pos;
            } else {
                npos[i * 27 + slot] = -1;   // dropped pair: skip in fixup
            }
            ++slot;
        }
    }
}

// ---------------- conv1: Cin=3 -> 128, compacted gather, bf16 out ----------
// One wave per voxel; lane owns channels (2l, 2l+1). Center term unconditional;
// then exactly vcnt[i] correction entries (wave-uniform trip count).
__global__ __launch_bounds__(256) void conv1_kernel(
    const float* __restrict__ feat, const float* __restrict__ w1,
    const int* __restrict__ vcnt, const int* __restrict__ nbrc,
    unsigned short* __restrict__ hout, int n) {
    const int wave = threadIdx.x >> 6, lane = threadIdx.x & 63;
    const int i = blockIdx.x * 4 + wave;
    if (i >= n) return;
    const int c2 = lane * 2;

    const int cnt = vcnt[i];
    float f0 = feat[i * 3 + 0];
    float f1 = feat[i * 3 + 1];
    float f2 = feat[i * 3 + 2];

    const float* wc = w1 + 13 * 384 + c2;
    float2 w0 = *(const float2*)(wc);
    float2 wv1 = *(const float2*)(wc + 128);
    float2 w2_ = *(const float2*)(wc + 256);
    float a0 = f0 * w0.x + f1 * wv1.x + f2 * w2_.x;
    float a1 = f0 * w0.y + f1 * wv1.y + f2 * w2_.y;

    for (int s = 0; s < cnt; ++s) {          // wave-uniform trip count
        int e = nbrc[i * 27 + s];
        int k = e >> 20, j = e & 0xFFFFF;
        float g0 = feat[j * 3 + 0];
        float g1 = feat[j * 3 + 1];
        float g2 = feat[j * 3 + 2];
        const float* wk = w1 + k * 384 + c2;
        float2 u0 = *(const float2*)(wk);
        float2 u1 = *(const float2*)(wk + 128);
        float2 u2 = *(const float2*)(wk + 256);
        a0 += g0 * u0.x + g1 * u1.x + g2 * u2.x;
        a1 += g0 * u0.y + g1 * u1.y + g2 * u2.y;
    }

    unsigned int packed = (unsigned int)f32_to_bf16(a0) |
                          ((unsigned int)f32_to_bf16(a1) << 16);
    *(unsigned int*)(hout + (size_t)i * 128 + c2) = packed;
}

// ---------------- conv2b: correction pairs, gather-GEMM -> corr rows --------
// NO atomics: tile row r of bucket kb stores its full 128-col f32 result to
// corr[(kb*CAP+base+r)*128 + col]. conv2a gathers these per voxel afterwards.
__global__ __launch_bounds__(256, 2) void conv2b_kernel(
    const unsigned short* __restrict__ h,
    const unsigned short* __restrict__ w2s,
    const int* __restrict__ pairs, const int* __restrict__ cnts,
    const unsigned short* __restrict__ zeropage,
    float* __restrict__ corr) {
    __shared__ __align__(16) unsigned char Alds[32768];
    __shared__ __align__(16) unsigned char Blds[32768];

    const int kb = blockIdx.x >> 5;
    const int tile = blockIdx.x & 31;
    const int cnt = min(cnts[kb * CNTS], CAP);
    const int base = tile * 128;
    if (base >= cnt) return;  // uniform early-exit (before any barrier)
    const int m = min(128, cnt - base);
    const int k = kb + (kb >= 13);
    const int* pk = pairs + kb * CAP + base;

    const int t = threadIdx.x;
    const int wave = t >> 6, lane = t & 63;
    const int lane16 = lane & 15, quad = lane >> 4;
    const int wm = wave >> 1, wn = wave & 1;

    if (wave < 2) {
        const int rbase = wave * 64;
#pragma unroll
        for (int it = 0; it < 16; ++it) {
            int r = rbase + it * 4 + quad;
            int j = (r < m) ? pk[r] : -1;
            int scc = ((lane & 7) ^ (r & 7)) | (lane & 8);
            const unsigned short* src =
                (j >= 0) ? (h + (size_t)j * 128 + scc * 8) : (zeropage + scc * 8);
            async_load16(src, &Alds[(rbase + it * 4) * 256]);
        }
    } else {
        const int rbase = (wave - 2) * 64;
        const unsigned short* w2k = w2s + k * 16384;
#pragma unroll
        for (int it = 0; it < 16; ++it) {
            int chunk = (rbase + it * 4) * 16 + lane;
            async_load16(w2k + chunk * 8, &Blds[(rbase + it * 4) * 256]);
        }
    }

    f32x4 acc[4][4];
#pragma unroll
    for (int a = 0; a < 4; ++a)
#pragma unroll
        for (int b = 0; b < 4; ++b) acc[a][b] = (f32x4){0.f, 0.f, 0.f, 0.f};

    __syncthreads();  // drains vmcnt(0): DMA complete

#pragma unroll
    for (int ks = 0; ks < 4; ++ks) {
        const int q = ks * 4 + quad;
        short8 a[4];
#pragma unroll
        for (int ms = 0; ms < 4; ++ms) {
            int mm = wm * 64 + ms * 16 + lane16;
            int pos = ((q & 7) ^ (mm & 7)) | (q & 8);
            a[ms] = *(const short8*)&Alds[mm * 256 + pos * 16];
        }
#pragma unroll
        for (int ns = 0; ns < 4; ++ns) {
            int c = wn * 64 + ns * 16 + lane16;
            int pos = ((q & 7) ^ (c & 7)) | (q & 8);
            short8 b = *(const short8*)&Blds[c * 256 + pos * 16];
#pragma unroll
            for (int ms = 0; ms < 4; ++ms)
                acc[ms][ns] = __builtin_amdgcn_mfma_f32_16x16x32_bf16(
                    a[ms], b, acc[ms][ns], 0, 0, 0);
        }
    }

    // plain coalesced stores of correction rows (64 B per quad per ns)
#pragma unroll
    for (int ms = 0; ms < 4; ++ms) {
#pragma unroll
        for (int r = 0; r < 4; ++r) {
            int row = wm * 64 + ms * 16 + quad * 4 + r;
            if (row < m) {
                float* cr = corr + (size_t)(kb * CAP + base + row) * 128;
#pragma unroll
                for (int ns = 0; ns < 4; ++ns) {
                    int col = wn * 64 + ns * 16 + lane16;
                    cr[col] = acc[ms][ns][r];
                }
            }
        }
    }
}

// ---------------- conv2a: dense center GEMM + correction gather ------------
// out[i] = h @ w2[13] + sum_s corr[npos[i][s]]  -- out written exactly once.
__global__ __launch_bounds__(256, 2) void conv2a_kernel(
    const unsigned short* __restrict__ h,
    const unsigned short* __restrict__ w2s,
    const unsigned short* __restrict__ zeropage,
    const int* __restrict__ vcnt, const int* __restrict__ npos,
    const float* __restrict__ corr,
    float* __restrict__ out, int n) {
    __shared__ __align__(16) unsigned char Alds[32768];  // 128 rows x 256B
    __shared__ __align__(16) unsigned char Blds[32768];

    const int t = threadIdx.x;
    const int wave = t >> 6, lane = t & 63;
    const int lane16 = lane & 15, quad = lane >> 4;
    const int wm = wave >> 1, wn = wave & 1;
    const int row0 = blockIdx.x * 128;

    if (wave < 2) {
        const int rbase = wave * 64;
#pragma unroll
        for (int it = 0; it < 16; ++it) {
            int r = rbase + it * 4 + quad;
            int i = row0 + r;
            int scc = ((lane & 7) ^ (r & 7)) | (lane & 8);
            const unsigned short* src =
                (i < n) ? (h + (size_t)i * 128 + scc * 8) : (zeropage + scc * 8);
            async_load16(src, &Alds[(rbase + it * 4) * 256]);
        }
    } else {
        const int rbase = (wave - 2) * 64;
        const unsigned short* w2k = w2s + 13 * 16384;
#pragma unroll
        for (int it = 0; it < 16; ++it) {
            int chunk = (rbase + it * 4) * 16 + lane;
            async_load16(w2k + chunk * 8, &Blds[(rbase + it * 4) * 256]);
        }
    }

    f32x4 acc[4][4];
#pragma unroll
    for (int a = 0; a < 4; ++a)
#pragma unroll
        for (int b = 0; b < 4; ++b) acc[a][b] = (f32x4){0.f, 0.f, 0.f, 0.f};

    __syncthreads();  // drains vmcnt(0): DMA complete

#pragma unroll
    for (int ks = 0; ks < 4; ++ks) {
        const int q = ks * 4 + quad;
        short8 a[4];
#pragma unroll
        for (int ms = 0; ms < 4; ++ms) {
            int m = wm * 64 + ms * 16 + lane16;
            int pos = ((q & 7) ^ (m & 7)) | (q & 8);
            a[ms] = *(const short8*)&Alds[m * 256 + pos * 16];
        }
#pragma unroll
        for (int ns = 0; ns < 4; ++ns) {
            int c = wn * 64 + ns * 16 + lane16;
            int pos = ((q & 7) ^ (c & 7)) | (q & 8);
            short8 b = *(const short8*)&Blds[c * 256 + pos * 16];
#pragma unroll
            for (int ms = 0; ms < 4; ++ms)
                acc[ms][ns] = __builtin_amdgcn_mfma_f32_16x16x32_bf16(
                    a[ms], b, acc[ms][ns], 0, 0, 0);
        }
    }

#pragma unroll
    for (int ms = 0; ms < 4; ++ms) {
#pragma unroll
        for (int r = 0; r < 4; ++r) {
            int i = row0 + wm * 64 + ms * 16 + quad * 4 + r;
            if (i < n) {
                // gather this row's correction rows (avg vcnt ~0.47)
                const int cnt = vcnt[i];
                const int* np = npos + i * 27;          // quad-uniform loads
                for (int s = 0; s < cnt; ++s) {
                    int p = np[s];
                    if (p >= 0) {
                        const float* cr =
                            corr + (size_t)p * 128 + wn * 64 + lane16;
                        acc[ms][0][r] += cr[0];
                        acc[ms][1][r] += cr[16];
                        acc[ms][2][r] += cr[32];
                        acc[ms][3][r] += cr[48];
                    }
                }
#pragma unroll
                for (int ns = 0; ns < 4; ++ns) {
                    int col = wn * 64 + ns * 16 + lane16;
                    out[(size_t)i * 128 + col] = acc[ms][ns][r];
                }
            }
        }
    }
}

// ---------------- launch ----------------
extern "C" void kernel_launch(void* const* d_in, const int* in_sizes, int n_in,
                              void* d_out, int out_size, void* d_ws,
                              size_t ws_size, hipStream_t stream) {
    const float* feat = (const float*)d_in[0];   // [n][3] f32
    const int* coors = (const int*)d_in[1];      // [n][4] i32
    const float* w1 = (const float*)d_in[2];     // [27][3][128] f32
    const float* w2 = (const float*)d_in[3];     // [27][128][128] f32
    float* out = (float*)d_out;                  // [n][128] f32

    const int n = in_sizes[0] / 3;

    uint8_t* ws = (uint8_t*)d_ws;
    size_t off = 0;
    int* grid = (int*)(ws + off); off += (size_t)GDHW * 4;            // 32 MB
    int* vcnt = (int*)(ws + off); off += (size_t)n * 4;               // 0.6 MB
    int* nbrc = (int*)(ws + off); off += (size_t)n * 27 * 4;          // 16.2 MB
    int* npos = (int*)(ws + off); off += (size_t)n * 27 * 4;          // 16.2 MB
    off = (off + 255) & ~(size_t)255;
    unsigned short* hbuf = (unsigned short*)(ws + off);
    off += (size_t)n * 128 * 2;                                       // 38.4 MB
    off = (off + 255) & ~(size_t)255;
    unsigned short* w2s = (unsigned short*)(ws + off);
    off += (size_t)KOFF * 128 * 128 * 2;                              // 0.85 MB
    off = (off + 255) & ~(size_t)255;
    int* pairs = (int*)(ws + off);
    off += (size_t)26 * CAP * 4;                                      // 0.43 MB
    off = (off + 255) & ~(size_t)255;
    int* cnts = (int*)(ws + off); off += 26 * CNTS * 4;               // 3.3 KB
    off = (off + 255) & ~(size_t)255;
    unsigned short* zerop = (unsigned short*)(ws + off); off += 256;
    off = (off + 255) & ~(size_t)255;
    float* corr = (float*)(ws + off);
    off += (size_t)26 * CAP * 128 * 4;                                // 54.5 MB

    hipMemsetAsync(grid, 0xFF, (size_t)GDHW * 4, stream);  // grid = -1

    const int nbsc = (n + 255) / 256;
    const int nbw2 = (NW2 + 255) / 256;
    setup_kernel<<<nbsc + nbw2, 256, 0, stream>>>(coors, grid, w2, w2s, cnts,
                                                  zerop, n, nbsc);
    nbr_kernel<<<nbsc, 256, 0, stream>>>(coors, grid, vcnt, nbrc, pairs, npos,
                                         cnts, n);
    conv1_kernel<<<(n + 3) / 4, 256, 0, stream>>>(feat, w1, vcnt, nbrc, hbuf, n);
    conv2b_kernel<<<26 * 32, 256, 0, stream>>>(hbuf, w2s, pairs, cnts, zerop,
                                               corr);
    conv2a_kernel<<<(n + 127) / 128, 256, 0, stream>>>(hbuf, w2s, zerop, vcnt,
                                                       npos, corr, out, n);
}

// Round 2
// 241.146 us; speedup vs baseline: 1.0931x; 1.0931x over previous
//
#include <hip/hip_runtime.h>
#include <stdint.h>

// ---------------- problem constants ----------------
#define GD 32
#define GH 512
#define GW 512
#define GDHW (GD * GH * GW)    // 8388608
#define KOFF 27
#define CAP 4096               // per-offset pair capacity (mean ~2685, sigma ~51)
#define CNTS 32                // counter stride in ints (128 B: one line each)
#define NW2 (KOFF * 128 * 128)

typedef __attribute__((ext_vector_type(8))) short short8;
typedef __attribute__((ext_vector_type(4))) float f32x4;

__device__ __forceinline__ unsigned short f32_to_bf16(float x) {
    unsigned int u = __float_as_uint(x);
    unsigned int r = (u + 0x7FFFu + ((u >> 16) & 1u)) >> 16;
    return (unsigned short)r;
}

// ---------------- setup: scatter + w2prep + tiny zero-fills (fused) --------
// w2  (f32)  : [27][128(cin)][128(cout)]
// w2t (bf16) : [27][128(cout)][128(cin)]  -- plain transpose, MFMA-B friendly
__global__ __launch_bounds__(256) void setup_kernel(
    const int* __restrict__ coors, int* __restrict__ grid,
    const float* __restrict__ w2, unsigned short* __restrict__ w2t,
    int* __restrict__ cnts, int n, int nbsc) {
    const int bid = blockIdx.x, t = threadIdx.x;
    if (bid == 0) {
        for (int q = t; q < 26 * CNTS; q += 256) cnts[q] = 0;
    }
    if (bid < nbsc) {
        int i = bid * 256 + t;
        if (i < n) {
            int z = coors[i * 4 + 1];
            int y = coors[i * 4 + 2];
            int x = coors[i * 4 + 3];
            grid[(z * GH + y) * GW + x] = i;
        }
    } else {
        int g = (bid - nbsc) * 256 + t;
        if (g < NW2) {
            int k = g >> 14;           // offset
            int c = (g >> 7) & 127;    // cout
            int q = g & 127;           // cin
            w2t[g] = f32_to_bf16(w2[(k * 128 + q) * 128 + c]);
        }
    }
}

// ---------------- nbr: SINGLE PASS, 26 branch-free probes (center j=i) ------
// Outputs:
//   vcnt[i] (all i<n written -> no memset), nbrc[i*27+s] = (k<<20)|j  -> conv1
//   pairs[kb][pos] = (i, j)                  -> conv2b gather + atomic scatter
__global__ __launch_bounds__(256) void nbr_kernel(
    const int* __restrict__ coors, const int* __restrict__ grid,
    int* __restrict__ vcnt, int* __restrict__ nbrc,
    int2* __restrict__ pairs, int* __restrict__ cnts, int n) {
    __shared__ int wcnt[4][26];
    __shared__ int kbase[26];

    const int i = blockIdx.x * 256 + threadIdx.x;
    const int t = threadIdx.x, wave = t >> 6, lane = t & 63;
    const bool live = (i < n);
    const unsigned long long lmask = (1ull << lane) - 1;

    int z = 0, y = 0, x = 0;
    if (live) {
        z = coors[i * 4 + 1];
        y = coors[i * 4 + 2];
        x = coors[i * 4 + 3];
    }

    // ---- phase 1: 26 branch-free clamped lookups (MLP=26) ----
    int j[27];
#pragma unroll
    for (int k = 0; k < 27; ++k) {
        if (k == 13) { j[k] = live ? i : -1; continue; }
        int dz = k / 9 - 1, dy = (k / 3) % 3 - 1, dx = k % 3 - 1;
        int nz = z + dz, ny = y + dy, nx = x + dx;
        int cz = min(max(nz, 0), GD - 1);
        int cy = min(max(ny, 0), GH - 1);
        int cx = min(max(nx, 0), GW - 1);
        int jj = grid[(cz * GH + cy) * GW + cx];   // always legal address
        bool ok = live && nz >= 0 && nz < GD && ny >= 0 && ny < GH &&
                  nx >= 0 && nx < GW;
        j[k] = ok ? jj : -1;
    }

    // ---- phase 2: per-voxel compacted list (single owner -> plain stores) --
    if (live) {
        int c = 0;
#pragma unroll
        for (int k = 0; k < 27; ++k) {
            if (k == 13) continue;
            if (j[k] >= 0) { nbrc[i * 27 + c] = (k << 20) | j[k]; ++c; }
        }
        vcnt[i] = c;
    }

    // ---- phase 3: per-offset pair buckets (block-aggregated atomic) ----
#pragma unroll
    for (int kk = 0; kk < 26; ++kk) {
        const int k = kk + (kk >= 13);
        unsigned long long m = __ballot(live && (j[k] >= 0));
        if (lane == 0) wcnt[wave][kk] = __popcll(m);
    }
    __syncthreads();
    if (t < 26) {
        int tot = wcnt[0][t] + wcnt[1][t] + wcnt[2][t] + wcnt[3][t];
        kbase[t] = (tot > 0) ? atomicAdd(&cnts[t * CNTS], tot) : 0;
    }
    __syncthreads();
#pragma unroll
    for (int kk = 0; kk < 26; ++kk) {
        const int k = kk + (kk >= 13);
        const bool valid = live && (j[k] >= 0);
        unsigned long long m = __ballot(valid);
        if (valid) {
            int off = 0;
#pragma unroll
            for (int w = 0; w < 4; ++w)
                if (w < wave) off += wcnt[w][kk];
            int pos = kbase[kk] + off + __popcll(m & lmask);
            if (pos < CAP) pairs[kk * CAP + pos] = make_int2(i, j[k]);
        }
    }
}

// ---------------- conv1: Cin=3 -> 128, compacted gather, bf16 out ----------
__global__ __launch_bounds__(256) void conv1_kernel(
    const float* __restrict__ feat, const float* __restrict__ w1,
    const int* __restrict__ vcnt, const int* __restrict__ nbrc,
    unsigned short* __restrict__ hout, int n) {
    const int wave = threadIdx.x >> 6, lane = threadIdx.x & 63;
    const int i = blockIdx.x * 4 + wave;
    if (i >= n) return;
    const int c2 = lane * 2;

    const int cnt = vcnt[i];
    float f0 = feat[i * 3 + 0];
    float f1 = feat[i * 3 + 1];
    float f2 = feat[i * 3 + 2];

    const float* wc = w1 + 13 * 384 + c2;
    float2 w0 = *(const float2*)(wc);
    float2 wv1 = *(const float2*)(wc + 128);
    float2 w2_ = *(const float2*)(wc + 256);
    float a0 = f0 * w0.x + f1 * wv1.x + f2 * w2_.x;
    float a1 = f0 * w0.y + f1 * wv1.y + f2 * w2_.y;

    for (int s = 0; s < cnt; ++s) {          // wave-uniform trip count
        int e = nbrc[i * 27 + s];
        int k = e >> 20, j = e & 0xFFFFF;
        float g0 = feat[j * 3 + 0];
        float g1 = feat[j * 3 + 1];
        float g2 = feat[j * 3 + 2];
        const float* wk = w1 + k * 384 + c2;
        float2 u0 = *(const float2*)(wk);
        float2 u1 = *(const float2*)(wk + 128);
        float2 u2 = *(const float2*)(wk + 256);
        a0 += g0 * u0.x + g1 * u1.x + g2 * u2.x;
        a1 += g0 * u0.y + g1 * u1.y + g2 * u2.y;
    }

    unsigned int packed = (unsigned int)f32_to_bf16(a0) |
                          ((unsigned int)f32_to_bf16(a1) << 16);
    *(unsigned int*)(hout + (size_t)i * 128 + c2) = packed;
}

// ---------------- conv2a: dense center GEMM, LDS-free register MFMA --------
// out[i] = h[i] @ w2t[13].  A/B fragments loaded straight into VGPRs:
// a[ms][ks] = h[row][ (ks*4+quad)*8 .. +8 ), row = row0+wm*64+ms*16+lane16
// 16 lanes x 16B = 16 full 64B lines per wave load -> fully coalesced.
// No LDS, no barrier: waves independently overlap 32-deep loads with MFMA.
__global__ __launch_bounds__(256, 2) void conv2a_kernel(
    const unsigned short* __restrict__ h,
    const unsigned short* __restrict__ w2t,
    float* __restrict__ out, int n) {
    const int t = threadIdx.x;
    const int wave = t >> 6, lane = t & 63;
    const int lane16 = lane & 15, quad = lane >> 4;
    const int wm = wave >> 1, wn = wave & 1;
    const int row0 = blockIdx.x * 128;

    short8 a[4][4];
#pragma unroll
    for (int ms = 0; ms < 4; ++ms) {
        int r = row0 + wm * 64 + ms * 16 + lane16;
        r = min(r, n - 1);                        // clamp: dup rows, never OOB
        const unsigned short* hp = h + (size_t)r * 128 + quad * 8;
#pragma unroll
        for (int ks = 0; ks < 4; ++ks)
            a[ms][ks] = *(const short8*)(hp + ks * 32);
    }

    short8 b[4][4];
    const unsigned short* wbase = w2t + 13 * 16384 + quad * 8;
#pragma unroll
    for (int ns = 0; ns < 4; ++ns) {
        int c = wn * 64 + ns * 16 + lane16;
        const unsigned short* wp = wbase + c * 128;
#pragma unroll
        for (int ks = 0; ks < 4; ++ks)
            b[ns][ks] = *(const short8*)(wp + ks * 32);
    }

    f32x4 acc[4][4];
#pragma unroll
    for (int p = 0; p < 4; ++p)
#pragma unroll
        for (int q = 0; q < 4; ++q) acc[p][q] = (f32x4){0.f, 0.f, 0.f, 0.f};

#pragma unroll
    for (int ks = 0; ks < 4; ++ks)
#pragma unroll
        for (int ns = 0; ns < 4; ++ns)
#pragma unroll
            for (int ms = 0; ms < 4; ++ms)
                acc[ms][ns] = __builtin_amdgcn_mfma_f32_16x16x32_bf16(
                    a[ms][ks], b[ns][ks], acc[ms][ns], 0, 0, 0);

#pragma unroll
    for (int ms = 0; ms < 4; ++ms) {
#pragma unroll
        for (int r = 0; r < 4; ++r) {
            int i = row0 + wm * 64 + ms * 16 + quad * 4 + r;
            if (i < n) {
#pragma unroll
                for (int ns = 0; ns < 4; ++ns) {
                    int col = wn * 64 + ns * 16 + lane16;
                    out[(size_t)i * 128 + col] = acc[ms][ns][r];
                }
            }
        }
    }
}

// ---------------- conv2b: correction pairs, register gather-GEMM-scatter ---
__global__ __launch_bounds__(256, 2) void conv2b_kernel(
    const unsigned short* __restrict__ h,
    const unsigned short* __restrict__ w2t,
    const int2* __restrict__ pairs, const int* __restrict__ cnts,
    float* __restrict__ out) {
    const int kb = blockIdx.x >> 5;
    const int tile = blockIdx.x & 31;
    const int cnt = min(cnts[kb * CNTS], CAP);
    const int base = tile * 128;
    if (base >= cnt) return;              // uniform early-exit
    const int m = min(128, cnt - base);
    const int k = kb + (kb >= 13);
    const int2* pk = pairs + kb * CAP + base;

    const int t = threadIdx.x;
    const int wave = t >> 6, lane = t & 63;
    const int lane16 = lane & 15, quad = lane >> 4;
    const int wm = wave >> 1, wn = wave & 1;

    short8 a[4][4];
#pragma unroll
    for (int ms = 0; ms < 4; ++ms) {
        int r = wm * 64 + ms * 16 + lane16;
        bool v = (r < m);
        int j = v ? pk[r].y : 0;
        const unsigned short* hp = h + (size_t)j * 128 + quad * 8;
#pragma unroll
        for (int ks = 0; ks < 4; ++ks)
            a[ms][ks] = v ? *(const short8*)(hp + ks * 32)
                          : (short8){0, 0, 0, 0, 0, 0, 0, 0};
    }

    short8 b[4][4];
    const unsigned short* wbase = w2t + (size_t)k * 16384 + quad * 8;
#pragma unroll
    for (int ns = 0; ns < 4; ++ns) {
        int c = wn * 64 + ns * 16 + lane16;
        const unsigned short* wp = wbase + c * 128;
#pragma unroll
        for (int ks = 0; ks < 4; ++ks)
            b[ns][ks] = *(const short8*)(wp + ks * 32);
    }

    f32x4 acc[4][4];
#pragma unroll
    for (int p = 0; p < 4; ++p)
#pragma unroll
        for (int q = 0; q < 4; ++q) acc[p][q] = (f32x4){0.f, 0.f, 0.f, 0.f};

#pragma unroll
    for (int ks = 0; ks < 4; ++ks)
#pragma unroll
        for (int ns = 0; ns < 4; ++ns)
#pragma unroll
            for (int ms = 0; ms < 4; ++ms)
                acc[ms][ns] = __builtin_amdgcn_mfma_f32_16x16x32_bf16(
                    a[ms][ks], b[ns][ks], acc[ms][ns], 0, 0, 0);

#pragma unroll
    for (int ms = 0; ms < 4; ++ms) {
#pragma unroll
        for (int r = 0; r < 4; ++r) {
            int row = wm * 64 + ms * 16 + quad * 4 + r;
            if (row < m) {
                int pi = pk[row].x;  // broadcast within the 16-lane quad
#pragma unroll
                for (int ns = 0; ns < 4; ++ns) {
                    int col = wn * 64 + ns * 16 + lane16;
                    unsafeAtomicAdd(&out[(size_t)pi * 128 + col], acc[ms][ns][r]);
                }
            }
        }
    }
}

// ---------------- launch ----------------
extern "C" void kernel_launch(void* const* d_in, const int* in_sizes, int n_in,
                              void* d_out, int out_size, void* d_ws,
                              size_t ws_size, hipStream_t stream) {
    const float* feat = (const float*)d_in[0];   // [n][3] f32
    const int* coors = (const int*)d_in[1];      // [n][4] i32
    const float* w1 = (const float*)d_in[2];     // [27][3][128] f32
    const float* w2 = (const float*)d_in[3];     // [27][128][128] f32
    float* out = (float*)d_out;                  // [n][128] f32

    const int n = in_sizes[0] / 3;

    uint8_t* ws = (uint8_t*)d_ws;
    size_t off = 0;
    int* grid = (int*)(ws + off); off += (size_t)GDHW * 4;            // 32 MB
    int* vcnt = (int*)(ws + off); off += (size_t)n * 4;               // 0.6 MB
    int* nbrc = (int*)(ws + off); off += (size_t)n * 27 * 4;          // 16.2 MB
    off = (off + 255) & ~(size_t)255;
    unsigned short* hbuf = (unsigned short*)(ws + off);
    off += (size_t)n * 128 * 2;                                       // 38.4 MB
    off = (off + 255) & ~(size_t)255;
    unsigned short* w2t = (unsigned short*)(ws + off);
    off += (size_t)KOFF * 128 * 128 * 2;                              // 0.85 MB
    off = (off + 255) & ~(size_t)255;
    int2* pairs = (int2*)(ws + off);
    off += (size_t)26 * CAP * sizeof(int2);                           // 0.85 MB
    off = (off + 255) & ~(size_t)255;
    int* cnts = (int*)(ws + off); off += 26 * CNTS * 4;               // 3.3 KB

    hipMemsetAsync(grid, 0xFF, (size_t)GDHW * 4, stream);  // grid = -1

    const int nbsc = (n + 255) / 256;
    const int nbw2 = (NW2 + 255) / 256;
    setup_kernel<<<nbsc + nbw2, 256, 0, stream>>>(coors, grid, w2, w2t, cnts,
                                                  n, nbsc);
    nbr_kernel<<<nbsc, 256, 0, stream>>>(coors, grid, vcnt, nbrc, pairs, cnts,
                                         n);
    conv1_kernel<<<(n + 3) / 4, 256, 0, stream>>>(feat, w1, vcnt, nbrc, hbuf, n);
    conv2a_kernel<<<(n + 127) / 128, 256, 0, stream>>>(hbuf, w2t, out, n);
    conv2b_kernel<<<26 * 32, 256, 0, stream>>>(hbuf, w2t, pairs, cnts, out);
}